// Round 7
// baseline (25.025 us; speedup 1.0000x reference)
//
#include <hip/hip_runtime.h>

#define MDIM 256
#define BATCH 256
#define DIMINISH 0.5f
#define RPB 8                       // rows per block (slab)
#define SLABS (MDIM / RPB)          // 32 slabs per batch
#define NBLK (BATCH * SLABS)        // 8192 blocks
#define NTHR 128                    // 2 waves per block

// Kernel 1: one 128-thread block per (batch, 8-row slab), slab-major order
// (longest jobs dispatch first; dead slabs exit after one scalar read).
// Each of the 2 waves owns 4 rows (r0+wid, +2, +4, +6) and issues ALL 16
// vector loads (4 rows x (2 int4 + 2 float4) = 512B/lane) before any
// compute. Rows >= dl inside the boundary slab are loaded anyway (in-bounds,
// ~4% extra traffic) and cancelled by an arithmetic row mask -> the load
// burst has no branches at all.
__global__ __launch_bounds__(NTHR, 4) void row_loss_kernel(
    const int*   __restrict__ y_true,
    const float* __restrict__ y_pred,
    const int*   __restrict__ doc_len,
    float*       __restrict__ partial)
{
    const int blk  = blockIdx.x;
    const int b    = blk & (BATCH - 1);           // batch varies fastest
    const int r0   = (blk >> 8) * RPB;            // slab-major
    const int dl   = doc_len[b];
    const int lane = threadIdx.x & 63;
    const int wid  = threadIdx.x >> 6;            // 0..1

    if (r0 >= dl) {                               // whole slab invalid
        if (threadIdx.x == 0) partial[blk] = 0.0f;
        return;
    }

    float sum = 0.0f;
    const int ra = r0 + wid;                      // wave's first row
    const int j0 = lane * 4;                      // first pair index for lane
    if (j0 < dl) {
        // element offset of row ra at pair j0; rows of this wave are ra+2k,
        // stride between them = 2 rows * 256 pairs * 2 elems = 1024 elements
        const size_t e = ((size_t)b * (MDIM * MDIM) + (size_t)ra * MDIM + (size_t)j0) * 2;

        int4   tA[4], tB[4];
        float4 pA[4], pB[4];
        #pragma unroll
        for (int k = 0; k < 4; ++k) {             // all 16 loads, no branches
            tA[k] = *reinterpret_cast<const int4*>(y_true + e + (size_t)k * 1024);
            tB[k] = *reinterpret_cast<const int4*>(y_true + e + (size_t)k * 1024 + 4);
            pA[k] = *reinterpret_cast<const float4*>(y_pred + e + (size_t)k * 1024);
            pB[k] = *reinterpret_cast<const float4*>(y_pred + e + (size_t)k * 1024 + 4);
        }
        __builtin_amdgcn_sched_barrier(0);        // keep the burst together

        // column masks (same for all rows)
        const float m1 = (j0 + 1 < dl) ? 1.0f : 0.0f;
        const float m2 = (j0 + 2 < dl) ? 1.0f : 0.0f;
        const float m3 = (j0 + 3 < dl) ? 1.0f : 0.0f;

        #pragma unroll
        for (int k = 0; k < 4; ++k) {
            const float rv = (ra + 2 * k < dl) ? 1.0f : 0.0f;   // row mask
            float s;
            s  =      ((float)tA[k].y * __logf(pA[k].y) + DIMINISH * (float)tA[k].x * __logf(pA[k].x));
            s += m1 * ((float)tA[k].w * __logf(pA[k].w) + DIMINISH * (float)tA[k].z * __logf(pA[k].z));
            s += m2 * ((float)tB[k].y * __logf(pB[k].y) + DIMINISH * (float)tB[k].x * __logf(pB[k].x));
            s += m3 * ((float)tB[k].w * __logf(pB[k].w) + DIMINISH * (float)tB[k].z * __logf(pB[k].z));
            sum -= rv * s;
        }
    }

    // wave shuffle reduction
    #pragma unroll
    for (int off = 32; off > 0; off >>= 1)
        sum += __shfl_down(sum, off, 64);

    __shared__ float wsum[2];
    if (lane == 0) wsum[wid] = sum;
    __syncthreads();
    if (threadIdx.x == 0)
        partial[blk] = wsum[0] + wsum[1];
}

// Kernel 2: deterministic reduction of 8192 partials + doc_len sum.
// 256 threads, 8 independent float4 loads each (all in flight).
__global__ __launch_bounds__(256) void final_reduce_kernel(
    const float* __restrict__ partial,
    const int*   __restrict__ doc_len,
    float*       __restrict__ out)
{
    const int t    = threadIdx.x;
    const int lane = t & 63;
    const int wid  = t >> 6;

    const float4* p4 = reinterpret_cast<const float4*>(partial);  // 2048 float4
    float4 v[8];
    #pragma unroll
    for (int k = 0; k < 8; ++k)
        v[k] = p4[t + k * 256];
    float d = (float)doc_len[t];                 // 256 threads == BATCH

    float s = 0.0f;
    #pragma unroll
    for (int k = 0; k < 8; ++k)
        s += (v[k].x + v[k].y) + (v[k].z + v[k].w);

    #pragma unroll
    for (int off = 32; off > 0; off >>= 1) {
        s += __shfl_down(s, off, 64);
        d += __shfl_down(d, off, 64);
    }

    __shared__ float wsum[4], wdl[4];
    if (lane == 0) { wsum[wid] = s; wdl[wid] = d; }
    __syncthreads();
    if (t == 0)
        out[0] = (wsum[0] + wsum[1] + wsum[2] + wsum[3]) /
                 (wdl[0]  + wdl[1]  + wdl[2]  + wdl[3]);
}

extern "C" void kernel_launch(void* const* d_in, const int* in_sizes, int n_in,
                              void* d_out, int out_size, void* d_ws, size_t ws_size,
                              hipStream_t stream)
{
    const int*   y_true  = (const int*)d_in[0];   // (B, M*M, 2) int32
    const float* y_pred  = (const float*)d_in[1]; // (B, M*M, 2) float32
    const int*   doc_len = (const int*)d_in[2];   // (B,) int32
    float*       out     = (float*)d_out;
    float*       partial = (float*)d_ws;          // 8192 floats = 32 KB

    row_loss_kernel<<<NBLK, NTHR, 0, stream>>>(y_true, y_pred, doc_len, partial);
    final_reduce_kernel<<<1, 256, 0, stream>>>(partial, doc_len, out);
}

// Round 8
// 24.410 us; speedup vs baseline: 1.0252x; 1.0252x over previous
//
#include <hip/hip_runtime.h>

#define MDIM 256
#define BATCH 256
#define DIMINISH 0.5f
#define RPB 16                      // rows per block (slab)
#define SLABS (MDIM / RPB)          // 16 slabs per batch
#define NBLK (BATCH * SLABS)        // 4096 blocks
#define NTHR 256                    // 4 waves per block

// Kernel 1: one 256-thread block per (batch, 16-row slab), slab-major order
// (longest jobs first; dead slabs exit after one scalar read). Each of the
// 4 waves owns 4 interleaved rows (r0+wid+4k) and issues ALL 16 vector loads
// (4 rows x (2 int4 + 2 float4) = 512B/lane) before any compute. Boundary-
// slab rows >= dl are loaded unconditionally (in-bounds, ~4% extra traffic)
// and cancelled by an arithmetic row mask -> branch-free load burst.
// Round-7 lesson: keep 256-thread blocks (128-thr blocks cost more than the
// deeper burst gained).
__global__ __launch_bounds__(NTHR, 2) void row_loss_kernel(
    const int*   __restrict__ y_true,
    const float* __restrict__ y_pred,
    const int*   __restrict__ doc_len,
    float*       __restrict__ partial)
{
    const int blk  = blockIdx.x;
    const int b    = blk & (BATCH - 1);           // batch varies fastest
    const int r0   = (blk >> 8) * RPB;            // slab-major
    const int dl   = doc_len[b];
    const int lane = threadIdx.x & 63;
    const int wid  = threadIdx.x >> 6;            // 0..3

    if (r0 >= dl) {                               // whole slab invalid
        if (threadIdx.x == 0) partial[blk] = 0.0f;
        return;
    }

    float sum = 0.0f;
    const int ra = r0 + wid;                      // wave's first row; rows ra+4k
    const int j0 = lane * 4;                      // first pair index for lane
    if (j0 < dl) {
        // stride between the wave's rows = 4 rows * 256 pairs * 2 = 2048 elems
        const size_t e = ((size_t)b * (MDIM * MDIM) + (size_t)ra * MDIM + (size_t)j0) * 2;

        int4   tA[4], tB[4];
        float4 pA[4], pB[4];
        #pragma unroll
        for (int k = 0; k < 4; ++k) {             // all 16 loads, no branches
            tA[k] = *reinterpret_cast<const int4*>(y_true + e + (size_t)k * 2048);
            tB[k] = *reinterpret_cast<const int4*>(y_true + e + (size_t)k * 2048 + 4);
            pA[k] = *reinterpret_cast<const float4*>(y_pred + e + (size_t)k * 2048);
            pB[k] = *reinterpret_cast<const float4*>(y_pred + e + (size_t)k * 2048 + 4);
        }
        __builtin_amdgcn_sched_barrier(0);        // keep the burst together

        // column masks (same for all rows)
        const float m1 = (j0 + 1 < dl) ? 1.0f : 0.0f;
        const float m2 = (j0 + 2 < dl) ? 1.0f : 0.0f;
        const float m3 = (j0 + 3 < dl) ? 1.0f : 0.0f;

        #pragma unroll
        for (int k = 0; k < 4; ++k) {
            const float rv = (ra + 4 * k < dl) ? 1.0f : 0.0f;   // row mask
            float s;
            s  =      ((float)tA[k].y * __logf(pA[k].y) + DIMINISH * (float)tA[k].x * __logf(pA[k].x));
            s += m1 * ((float)tA[k].w * __logf(pA[k].w) + DIMINISH * (float)tA[k].z * __logf(pA[k].z));
            s += m2 * ((float)tB[k].y * __logf(pB[k].y) + DIMINISH * (float)tB[k].x * __logf(pB[k].x));
            s += m3 * ((float)tB[k].w * __logf(pB[k].w) + DIMINISH * (float)tB[k].z * __logf(pB[k].z));
            sum -= rv * s;
        }
    }

    // wave shuffle reduction
    #pragma unroll
    for (int off = 32; off > 0; off >>= 1)
        sum += __shfl_down(sum, off, 64);

    __shared__ float wsum[4];
    if (lane == 0) wsum[wid] = sum;
    __syncthreads();
    if (threadIdx.x == 0)
        partial[blk] = wsum[0] + wsum[1] + wsum[2] + wsum[3];
}

// Kernel 2: deterministic reduction of 4096 partials + doc_len sum.
// 256 threads, 4 independent float4 loads each (all in flight).
__global__ __launch_bounds__(256) void final_reduce_kernel(
    const float* __restrict__ partial,
    const int*   __restrict__ doc_len,
    float*       __restrict__ out)
{
    const int t    = threadIdx.x;
    const int lane = t & 63;
    const int wid  = t >> 6;

    const float4* p4 = reinterpret_cast<const float4*>(partial);  // 1024 float4
    float4 v[4];
    #pragma unroll
    for (int k = 0; k < 4; ++k)
        v[k] = p4[t + k * 256];
    float d = (float)doc_len[t];                 // 256 threads == BATCH

    float s = 0.0f;
    #pragma unroll
    for (int k = 0; k < 4; ++k)
        s += (v[k].x + v[k].y) + (v[k].z + v[k].w);

    #pragma unroll
    for (int off = 32; off > 0; off >>= 1) {
        s += __shfl_down(s, off, 64);
        d += __shfl_down(d, off, 64);
    }

    __shared__ float wsum[4], wdl[4];
    if (lane == 0) { wsum[wid] = s; wdl[wid] = d; }
    __syncthreads();
    if (t == 0)
        out[0] = (wsum[0] + wsum[1] + wsum[2] + wsum[3]) /
                 (wdl[0]  + wdl[1]  + wdl[2]  + wdl[3]);
}

extern "C" void kernel_launch(void* const* d_in, const int* in_sizes, int n_in,
                              void* d_out, int out_size, void* d_ws, size_t ws_size,
                              hipStream_t stream)
{
    const int*   y_true  = (const int*)d_in[0];   // (B, M*M, 2) int32
    const float* y_pred  = (const float*)d_in[1]; // (B, M*M, 2) float32
    const int*   doc_len = (const int*)d_in[2];   // (B,) int32
    float*       out     = (float*)d_out;
    float*       partial = (float*)d_ws;          // 4096 floats = 16 KB

    row_loss_kernel<<<NBLK, NTHR, 0, stream>>>(y_true, y_pred, doc_len, partial);
    final_reduce_kernel<<<1, 256, 0, stream>>>(partial, doc_len, out);
}

// Round 9
// 23.914 us; speedup vs baseline: 1.0465x; 1.0207x over previous
//
#include <hip/hip_runtime.h>

#define MDIM 256
#define BATCH 256
#define DIMINISH 0.5f
#define RPB 8                       // rows per block (slab)
#define SLABS (MDIM / RPB)          // 32 slabs per batch
#define NBLK (BATCH * SLABS)        // 8192 blocks
#define NTHR 256

// ===== MEASUREMENT ROUND: kernels identical to Round 6 (best, 22.7us). =====
// kernel_launch runs final_reduce_kernel TWICE (idempotent, bit-identical
// output) so dur_us - 22.7 measures (graph gap + kernel2 duration) and
// discriminates "kernel1 slow" (H1) vs "launch overhead dominates" (H2).

__global__ __launch_bounds__(NTHR, 2) void row_loss_kernel(
    const int*   __restrict__ y_true,
    const float* __restrict__ y_pred,
    const int*   __restrict__ doc_len,
    float*       __restrict__ partial)
{
    const int blk  = blockIdx.x;
    const int b    = blk & (BATCH - 1);           // batch varies fastest
    const int r0   = (blk >> 8) * RPB;            // slab-major
    const int dl   = doc_len[b];
    const int lane = threadIdx.x & 63;
    const int wid  = threadIdx.x >> 6;

    if (r0 >= dl) {                               // whole slab invalid
        if (threadIdx.x == 0) partial[blk] = 0.0f;
        return;
    }

    float sum = 0.0f;
    const int r  = r0 + wid * 2;                  // wave's first row
    const int j0 = lane * 4;                      // first pair index for lane
    if (r < dl && j0 < dl) {
        const size_t e0 = ((size_t)b * (MDIM * MDIM) + (size_t)r * MDIM + (size_t)j0) * 2;
        const size_t e1 = e0 + 2 * MDIM;          // next row (r+1 <= 255, in-bounds)
        const int4   t0 = *reinterpret_cast<const int4*>(y_true + e0);
        const int4   t1 = *reinterpret_cast<const int4*>(y_true + e0 + 4);
        const int4   u0 = *reinterpret_cast<const int4*>(y_true + e1);
        const int4   u1 = *reinterpret_cast<const int4*>(y_true + e1 + 4);
        const float4 p0 = *reinterpret_cast<const float4*>(y_pred + e0);
        const float4 p1 = *reinterpret_cast<const float4*>(y_pred + e0 + 4);
        const float4 q0 = *reinterpret_cast<const float4*>(y_pred + e1);
        const float4 q1 = *reinterpret_cast<const float4*>(y_pred + e1 + 4);
        __builtin_amdgcn_sched_barrier(0);        // keep all loads issued first
        const float m1 = (j0 + 1 < dl) ? 1.0f : 0.0f;
        const float m2 = (j0 + 2 < dl) ? 1.0f : 0.0f;
        const float m3 = (j0 + 3 < dl) ? 1.0f : 0.0f;
        const float rv = (r + 1 < dl) ? 1.0f : 0.0f;   // second row validity
        float s0;
        s0  =      ((float)t0.y * __logf(p0.y) + DIMINISH * (float)t0.x * __logf(p0.x));
        s0 += m1 * ((float)t0.w * __logf(p0.w) + DIMINISH * (float)t0.z * __logf(p0.z));
        s0 += m2 * ((float)t1.y * __logf(p1.y) + DIMINISH * (float)t1.x * __logf(p1.x));
        s0 += m3 * ((float)t1.w * __logf(p1.w) + DIMINISH * (float)t1.z * __logf(p1.z));
        float s1;
        s1  =      ((float)u0.y * __logf(q0.y) + DIMINISH * (float)u0.x * __logf(q0.x));
        s1 += m1 * ((float)u0.w * __logf(q0.w) + DIMINISH * (float)u0.z * __logf(q0.z));
        s1 += m2 * ((float)u1.y * __logf(q1.y) + DIMINISH * (float)u1.x * __logf(q1.x));
        s1 += m3 * ((float)u1.w * __logf(q1.w) + DIMINISH * (float)u1.z * __logf(q1.z));
        sum = -(s0 + rv * s1);
    }

    #pragma unroll
    for (int off = 32; off > 0; off >>= 1)
        sum += __shfl_down(sum, off, 64);

    __shared__ float wsum[4];
    if (lane == 0) wsum[wid] = sum;
    __syncthreads();
    if (threadIdx.x == 0)
        partial[blk] = wsum[0] + wsum[1] + wsum[2] + wsum[3];
}

__global__ __launch_bounds__(256) void final_reduce_kernel(
    const float* __restrict__ partial,
    const int*   __restrict__ doc_len,
    float*       __restrict__ out)
{
    const int t    = threadIdx.x;
    const int lane = t & 63;
    const int wid  = t >> 6;

    const float4* p4 = reinterpret_cast<const float4*>(partial);  // 2048 float4
    float4 v[8];
    #pragma unroll
    for (int k = 0; k < 8; ++k)
        v[k] = p4[t + k * 256];
    float d = (float)doc_len[t];                 // 256 threads == BATCH

    float s = 0.0f;
    #pragma unroll
    for (int k = 0; k < 8; ++k)
        s += (v[k].x + v[k].y) + (v[k].z + v[k].w);

    #pragma unroll
    for (int off = 32; off > 0; off >>= 1) {
        s += __shfl_down(s, off, 64);
        d += __shfl_down(d, off, 64);
    }

    __shared__ float wsum[4], wdl[4];
    if (lane == 0) { wsum[wid] = s; wdl[wid] = d; }
    __syncthreads();
    if (t == 0)
        out[0] = (wsum[0] + wsum[1] + wsum[2] + wsum[3]) /
                 (wdl[0]  + wdl[1]  + wdl[2]  + wdl[3]);
}

extern "C" void kernel_launch(void* const* d_in, const int* in_sizes, int n_in,
                              void* d_out, int out_size, void* d_ws, size_t ws_size,
                              hipStream_t stream)
{
    const int*   y_true  = (const int*)d_in[0];   // (B, M*M, 2) int32
    const float* y_pred  = (const float*)d_in[1]; // (B, M*M, 2) float32
    const int*   doc_len = (const int*)d_in[2];   // (B,) int32
    float*       out     = (float*)d_out;
    float*       partial = (float*)d_ws;          // 8192 floats = 32 KB

    row_loss_kernel<<<NBLK, NTHR, 0, stream>>>(y_true, y_pred, doc_len, partial);
    final_reduce_kernel<<<1, 256, 0, stream>>>(partial, doc_len, out);
    // duplicate launch: idempotent; measures (graph gap + kernel2 duration)
    final_reduce_kernel<<<1, 256, 0, stream>>>(partial, doc_len, out);
}

// Round 10
// 22.873 us; speedup vs baseline: 1.0941x; 1.0455x over previous
//
#include <hip/hip_runtime.h>

#define MDIM 256
#define BATCH 256
#define DIMINISH 0.5f
#define RPB 8                       // rows per block (slab)
#define SLABS (MDIM / RPB)          // 32 slabs per batch
#define NBLK (BATCH * SLABS)        // 8192 blocks
#define NTHR 256

// FINAL (= Round-6 best, 22.7us): one 256-thread block per (batch, 8-row
// slab), slab-major order (longest jobs dispatch first; dead slabs exit after
// one scalar read). Each wave owns a row pair and issues all 8 16B loads
// before compute; masks are arithmetic. Verdict from R7/R8/R9 probes:
// kernel-1 runs at ~4.5 TB/s on a gappy stream (71% of copy ceiling) and a
// dense-rectangle restructure would cost the same time at 100% efficiency ->
// practical memory floor for this layout. kernel2+gap measured at 1.24us.
__global__ __launch_bounds__(NTHR, 2) void row_loss_kernel(
    const int*   __restrict__ y_true,
    const float* __restrict__ y_pred,
    const int*   __restrict__ doc_len,
    float*       __restrict__ partial)
{
    const int blk  = blockIdx.x;
    const int b    = blk & (BATCH - 1);           // batch varies fastest
    const int r0   = (blk >> 8) * RPB;            // slab-major
    const int dl   = doc_len[b];
    const int lane = threadIdx.x & 63;
    const int wid  = threadIdx.x >> 6;

    if (r0 >= dl) {                               // whole slab invalid
        if (threadIdx.x == 0) partial[blk] = 0.0f;
        return;
    }

    float sum = 0.0f;
    const int r  = r0 + wid * 2;                  // wave's first row
    const int j0 = lane * 4;                      // first pair index for lane
    if (r < dl && j0 < dl) {
        const size_t e0 = ((size_t)b * (MDIM * MDIM) + (size_t)r * MDIM + (size_t)j0) * 2;
        const size_t e1 = e0 + 2 * MDIM;          // next row (r+1 <= 255, in-bounds)
        const int4   t0 = *reinterpret_cast<const int4*>(y_true + e0);
        const int4   t1 = *reinterpret_cast<const int4*>(y_true + e0 + 4);
        const int4   u0 = *reinterpret_cast<const int4*>(y_true + e1);
        const int4   u1 = *reinterpret_cast<const int4*>(y_true + e1 + 4);
        const float4 p0 = *reinterpret_cast<const float4*>(y_pred + e0);
        const float4 p1 = *reinterpret_cast<const float4*>(y_pred + e0 + 4);
        const float4 q0 = *reinterpret_cast<const float4*>(y_pred + e1);
        const float4 q1 = *reinterpret_cast<const float4*>(y_pred + e1 + 4);
        __builtin_amdgcn_sched_barrier(0);        // keep all loads issued first
        const float m1 = (j0 + 1 < dl) ? 1.0f : 0.0f;
        const float m2 = (j0 + 2 < dl) ? 1.0f : 0.0f;
        const float m3 = (j0 + 3 < dl) ? 1.0f : 0.0f;
        const float rv = (r + 1 < dl) ? 1.0f : 0.0f;   // second row validity
        float s0;
        s0  =      ((float)t0.y * __logf(p0.y) + DIMINISH * (float)t0.x * __logf(p0.x));
        s0 += m1 * ((float)t0.w * __logf(p0.w) + DIMINISH * (float)t0.z * __logf(p0.z));
        s0 += m2 * ((float)t1.y * __logf(p1.y) + DIMINISH * (float)t1.x * __logf(p1.x));
        s0 += m3 * ((float)t1.w * __logf(p1.w) + DIMINISH * (float)t1.z * __logf(p1.z));
        float s1;
        s1  =      ((float)u0.y * __logf(q0.y) + DIMINISH * (float)u0.x * __logf(q0.x));
        s1 += m1 * ((float)u0.w * __logf(q0.w) + DIMINISH * (float)u0.z * __logf(q0.z));
        s1 += m2 * ((float)u1.y * __logf(q1.y) + DIMINISH * (float)u1.x * __logf(q1.x));
        s1 += m3 * ((float)u1.w * __logf(q1.w) + DIMINISH * (float)u1.z * __logf(q1.z));
        sum = -(s0 + rv * s1);
    }

    #pragma unroll
    for (int off = 32; off > 0; off >>= 1)
        sum += __shfl_down(sum, off, 64);

    __shared__ float wsum[4];
    if (lane == 0) wsum[wid] = sum;
    __syncthreads();
    if (threadIdx.x == 0)
        partial[blk] = wsum[0] + wsum[1] + wsum[2] + wsum[3];
}

__global__ __launch_bounds__(256) void final_reduce_kernel(
    const float* __restrict__ partial,
    const int*   __restrict__ doc_len,
    float*       __restrict__ out)
{
    const int t    = threadIdx.x;
    const int lane = t & 63;
    const int wid  = t >> 6;

    const float4* p4 = reinterpret_cast<const float4*>(partial);  // 2048 float4
    float4 v[8];
    #pragma unroll
    for (int k = 0; k < 8; ++k)
        v[k] = p4[t + k * 256];
    float d = (float)doc_len[t];                 // 256 threads == BATCH

    float s = 0.0f;
    #pragma unroll
    for (int k = 0; k < 8; ++k)
        s += (v[k].x + v[k].y) + (v[k].z + v[k].w);

    #pragma unroll
    for (int off = 32; off > 0; off >>= 1) {
        s += __shfl_down(s, off, 64);
        d += __shfl_down(d, off, 64);
    }

    __shared__ float wsum[4], wdl[4];
    if (lane == 0) { wsum[wid] = s; wdl[wid] = d; }
    __syncthreads();
    if (t == 0)
        out[0] = (wsum[0] + wsum[1] + wsum[2] + wsum[3]) /
                 (wdl[0]  + wdl[1]  + wdl[2]  + wdl[3]);
}

extern "C" void kernel_launch(void* const* d_in, const int* in_sizes, int n_in,
                              void* d_out, int out_size, void* d_ws, size_t ws_size,
                              hipStream_t stream)
{
    const int*   y_true  = (const int*)d_in[0];   // (B, M*M, 2) int32
    const float* y_pred  = (const float*)d_in[1]; // (B, M*M, 2) float32
    const int*   doc_len = (const int*)d_in[2];   // (B,) int32
    float*       out     = (float*)d_out;
    float*       partial = (float*)d_ws;          // 8192 floats = 32 KB

    row_loss_kernel<<<NBLK, NTHR, 0, stream>>>(y_true, y_pred, doc_len, partial);
    final_reduce_kernel<<<1, 256, 0, stream>>>(partial, doc_len, out);
}